// Round 2
// baseline (65.780 us; speedup 1.0000x reference)
//
#include <hip/hip_runtime.h>

// Problem constants (from reference):
#define BB 8
#define NN 32768
#define CC 4
#define MM 11          // memory length (FIR taps)
#define KK 55          // D*M
#define THREADS 256
#define KPT 2          // outputs per thread
#define OUT_PER_BLOCK (THREADS * KPT)   // 512
#define HALO (MM - 1)                   // 10
#define SS (OUT_PER_BLOCK + HALO)       // 522 staged samples per block
#define SEG ((SS + 1) / 2)              // 261 (parity-split segment length)

// out[b,c,n] = sum_{j=0..10} z[n-10+j] * ( sum_d W[c, d*11+j] * |z[n-10+j]|^d )
// z[t] = x[b,t,c,0] + i x[b,t,c,1], zero for t<0.
//
// KPT=2: thread computes outputs n=2*tid, 2*tid+1 from samples s=2*tid+k,
// k=0..11 -> 18 ds_read_b128/output instead of 33.
// Parity-split LDS layout slot(s) = (s&1)*SEG + (s>>1): consumer lane stride
// stays 1 slot = 12 dwords -> bank-balanced (8 lanes per 4-bank group, the
// b128 bandwidth floor).

__global__ __launch_bounds__(THREADS, 2)
void gmp_kernel(const float* __restrict__ x,
                const float* __restrict__ W,
                float* __restrict__ out) {
    __shared__ float4 smem[SS * 3];   // per slot: {lo(ch0,ch1), hi(ch2,ch3), amp4}

    const int tid = threadIdx.x;
    const int b = blockIdx.y;
    const int n0 = blockIdx.x * OUT_PER_BLOCK;

    const float4* xg = (const float4*)x + (size_t)b * NN * 2;

    // Stage samples t = n0-10 .. n0+511 (zero-fill t<0); amp computed once/sample.
    for (int s = tid; s < SS; s += THREADS) {
        const int t = n0 - HALO + s;
        float4 lo = make_float4(0.f, 0.f, 0.f, 0.f);
        float4 hi = lo;
        if (t >= 0) {
            lo = xg[2 * t];
            hi = xg[2 * t + 1];
        }
        float4 a;
        a.x = sqrtf(fmaf(lo.x, lo.x, lo.y * lo.y));
        a.y = sqrtf(fmaf(lo.z, lo.z, lo.w * lo.w));
        a.z = sqrtf(fmaf(hi.x, hi.x, hi.y * hi.y));
        a.w = sqrtf(fmaf(hi.z, hi.z, hi.w * hi.w));
        const int slot = ((s & 1) * SEG + (s >> 1)) * 3;
        smem[slot + 0] = lo;
        smem[slot + 1] = hi;
        smem[slot + 2] = a;
    }
    __syncthreads();

    float ar0[CC] = {0.f, 0.f, 0.f, 0.f}, ai0[CC] = {0.f, 0.f, 0.f, 0.f};
    float ar1[CC] = {0.f, 0.f, 0.f, 0.f}, ai1[CC] = {0.f, 0.f, 0.f, 0.f};

    #pragma unroll
    for (int k = 0; k < MM + 1; k++) {   // 12 samples: s = 2*tid + k
        // s&1 == k&1, s>>1 == tid + (k>>1)
        const int slot = ((k & 1) * SEG + tid + (k >> 1)) * 3;
        const float4 lo = smem[slot + 0];
        const float4 hi = smem[slot + 1];
        const float4 a  = smem[slot + 2];
        const float re[CC] = {lo.x, lo.z, hi.x, hi.z};
        const float im[CC] = {lo.y, lo.w, hi.y, hi.w};
        const float am[CC] = {a.x, a.y, a.z, a.w};
        #pragma unroll
        for (int c = 0; c < CC; c++) {
            if (k <= MM - 1) {   // tap j = k for output 0
                float p = W[c * KK + 4 * MM + k];
                p = fmaf(p, am[c], W[c * KK + 3 * MM + k]);
                p = fmaf(p, am[c], W[c * KK + 2 * MM + k]);
                p = fmaf(p, am[c], W[c * KK + 1 * MM + k]);
                p = fmaf(p, am[c], W[c * KK + 0 * MM + k]);
                ar0[c] = fmaf(re[c], p, ar0[c]);
                ai0[c] = fmaf(im[c], p, ai0[c]);
            }
            if (k >= 1) {        // tap j = k-1 for output 1
                float p = W[c * KK + 4 * MM + (k - 1)];
                p = fmaf(p, am[c], W[c * KK + 3 * MM + (k - 1)]);
                p = fmaf(p, am[c], W[c * KK + 2 * MM + (k - 1)]);
                p = fmaf(p, am[c], W[c * KK + 1 * MM + (k - 1)]);
                p = fmaf(p, am[c], W[c * KK + 0 * MM + (k - 1)]);
                ar1[c] = fmaf(re[c], p, ar1[c]);
                ai1[c] = fmaf(im[c], p, ai1[c]);
            }
        }
    }

    // out[b,n,c,{re,im}]: thread writes 2 outputs = 64 contiguous bytes.
    const int n = n0 + 2 * tid;
    float4* og = (float4*)out + (size_t)(b * NN + n) * 2;
    og[0] = make_float4(ar0[0], ai0[0], ar0[1], ai0[1]);
    og[1] = make_float4(ar0[2], ai0[2], ar0[3], ai0[3]);
    og[2] = make_float4(ar1[0], ai1[0], ar1[1], ai1[1]);
    og[3] = make_float4(ar1[2], ai1[2], ar1[3], ai1[3]);
}

extern "C" void kernel_launch(void* const* d_in, const int* in_sizes, int n_in,
                              void* d_out, int out_size, void* d_ws, size_t ws_size,
                              hipStream_t stream) {
    const float* x = (const float*)d_in[0];   // [B,N,C,2] fp32
    const float* W = (const float*)d_in[1];   // [C,K] fp32
    float* out = (float*)d_out;               // [B,N,C,2] fp32

    dim3 grid(NN / OUT_PER_BLOCK, BB);        // (64, 8) = 512 blocks
    gmp_kernel<<<grid, THREADS, 0, stream>>>(x, W, out);
}

// Round 3
// 62.519 us; speedup vs baseline: 1.0522x; 1.0522x over previous
//
#include <hip/hip_runtime.h>

// Problem constants (from reference):
#define BB 8
#define NN 32768
#define CC 4
#define MM 11          // memory length (FIR taps)
#define KK 55          // D*M
#define THREADS 256
#define HALO (MM - 1)              // 10
#define SS (THREADS + HALO)        // 266 staged samples per block

// out[b,c,n] = sum_{j=0..10} z[n-10+j] * ( sum_d W[c, d*11+j] * |z[n-10+j]|^d )
// z[t] = x[b,t,c,0] + i x[b,t,c,1], zero for t<0.
//
// Round-3 design: blockIdx.z selects a channel PAIR (h=0 -> ch0/1, h=1 -> ch2/3).
// Doubles total waves to 32/CU (full residency) for latency hiding; weight rows
// stay SGPR-uniform (h is a block index). Per-thread: 11 b128 + 11 b64 LDS
// reads, 132 fma. LDS access patterns are the canonical full-bandwidth strides
// (b128 @ 16B lane stride, b64 @ 8B).

__global__ __launch_bounds__(THREADS, 8)
void gmp_kernel(const float* __restrict__ x,
                const float* __restrict__ W,
                float* __restrict__ out) {
    __shared__ float4 zs[SS];    // (re0, im0, re1, im1) for this block's channel pair
    __shared__ float2 as2[SS];   // |z| for the two channels

    const int tid = threadIdx.x;
    const int b  = blockIdx.y;
    const int h  = blockIdx.z;               // channel pair: channels 2h, 2h+1
    const int n0 = blockIdx.x * THREADS;

    const float4* xg = (const float4*)x + (size_t)b * NN * 2;

    // Stage samples t = n0-10 .. n0+255 for this channel pair.
    for (int s = tid; s < SS; s += THREADS) {
        const int t = n0 - HALO + s;
        float4 v = make_float4(0.f, 0.f, 0.f, 0.f);
        if (t >= 0) v = xg[2 * t + h];
        float2 a;
        a.x = sqrtf(fmaf(v.x, v.x, v.y * v.y));
        a.y = sqrtf(fmaf(v.z, v.z, v.w * v.w));
        zs[s] = v;
        as2[s] = a;
    }
    __syncthreads();

    // Weight rows for this pair — wave-uniform (h is SGPR) -> scalar loads.
    const float* W0 = W + (2 * h) * KK;
    const float* W1 = W + (2 * h + 1) * KK;

    float ar0 = 0.f, ai0 = 0.f, ar1 = 0.f, ai1 = 0.f;

    #pragma unroll
    for (int j = 0; j < MM; j++) {
        const int s = tid + j;
        const float4 v = zs[s];
        const float2 a = as2[s];
        // channel 2h
        {
            float p = W0[4 * MM + j];
            p = fmaf(p, a.x, W0[3 * MM + j]);
            p = fmaf(p, a.x, W0[2 * MM + j]);
            p = fmaf(p, a.x, W0[1 * MM + j]);
            p = fmaf(p, a.x, W0[0 * MM + j]);
            ar0 = fmaf(v.x, p, ar0);
            ai0 = fmaf(v.y, p, ai0);
        }
        // channel 2h+1
        {
            float p = W1[4 * MM + j];
            p = fmaf(p, a.y, W1[3 * MM + j]);
            p = fmaf(p, a.y, W1[2 * MM + j]);
            p = fmaf(p, a.y, W1[1 * MM + j]);
            p = fmaf(p, a.y, W1[0 * MM + j]);
            ar1 = fmaf(v.z, p, ar1);
            ai1 = fmaf(v.w, p, ai1);
        }
    }

    // out[b,n,c,{re,im}]: this thread writes channels 2h,2h+1 -> 16 contiguous bytes.
    const int n = n0 + tid;
    float4* og = (float4*)out + ((size_t)(b * NN + n) * 2 + h);
    *og = make_float4(ar0, ai0, ar1, ai1);
}

extern "C" void kernel_launch(void* const* d_in, const int* in_sizes, int n_in,
                              void* d_out, int out_size, void* d_ws, size_t ws_size,
                              hipStream_t stream) {
    const float* x = (const float*)d_in[0];   // [B,N,C,2] fp32
    const float* W = (const float*)d_in[1];   // [C,K] fp32
    float* out = (float*)d_out;               // [B,N,C,2] fp32

    dim3 grid(NN / THREADS, BB, 2);           // 128 x 8 x 2 = 2048 blocks
    gmp_kernel<<<grid, THREADS, 0, stream>>>(x, W, out);
}